// Round 1
// baseline (545.920 us; speedup 1.0000x reference)
//
#include <hip/hip_runtime.h>

#define NN 50000
#define NE 800000

// ---------------- CSR build ----------------
__global__ void hist_kernel(const int* __restrict__ dst, int* __restrict__ deg, int ne) {
    int e = blockIdx.x * blockDim.x + threadIdx.x;
    if (e < ne) atomicAdd(&deg[dst[e]], 1);
}

__global__ __launch_bounds__(1024) void scan_kernel(const int* __restrict__ deg,
                                                    int* __restrict__ row_ptr,
                                                    float* __restrict__ inv_deg, int n) {
    __shared__ int ps[1024];
    int tid = threadIdx.x;
    int per = (n + 1023) >> 10;                 // 49 for n=50000
    int beg = tid * per;
    int end = beg + per;
    if (beg > n) beg = n;
    if (end > n) end = n;
    int s = 0;
    for (int i = beg; i < end; ++i) s += deg[i];
    ps[tid] = s;
    __syncthreads();
    // inclusive Hillis-Steele scan over 1024 partials
    for (int d = 1; d < 1024; d <<= 1) {
        int v = (tid >= d) ? ps[tid - d] : 0;
        __syncthreads();
        ps[tid] += v;
        __syncthreads();
    }
    int off = (tid == 0) ? 0 : ps[tid - 1];     // exclusive prefix
    for (int i = beg; i < end; ++i) {
        row_ptr[i] = off;
        int d = deg[i];
        inv_deg[i] = 1.0f / (float)(d > 0 ? d : 1);
        off += d;
    }
    if (tid == 1023) row_ptr[n] = off;          // total edge count
}

__global__ void fill_kernel(const int* __restrict__ src, const int* __restrict__ dst,
                            const int* __restrict__ row_ptr, int* __restrict__ fill,
                            int* __restrict__ col, int ne) {
    int e = blockIdx.x * blockDim.x + threadIdx.x;
    if (e >= ne) return;
    int d = dst[e];
    int pos = atomicAdd(&fill[d], 1);
    col[row_ptr[d] + pos] = src[e];
}

// ---------------- mean aggregation (gather over CSR) ----------------
// one 64-lane wave per node; lane handles 2 features (float2, 8B coalesced)
__global__ __launch_bounds__(256) void agg_kernel(const float* __restrict__ h,
                                                  const int* __restrict__ row_ptr,
                                                  const int* __restrict__ col,
                                                  const float* __restrict__ inv_deg,
                                                  float* __restrict__ out, int n) {
    int node = blockIdx.x * 4 + (threadIdx.x >> 6);
    if (node >= n) return;
    int lane = threadIdx.x & 63;
    int beg = row_ptr[node], end = row_ptr[node + 1];
    float ax = 0.f, ay = 0.f;
    for (int e = beg; e < end; ++e) {
        int j = col[e];                                  // wave-uniform -> scalar load
        float2 v = *(const float2*)(h + ((size_t)j << 7) + (lane << 1));
        ax += v.x;
        ay += v.y;
    }
    float s = inv_deg[node];
    float2 r;
    r.x = ax * s;
    r.y = ay * s;
    *(float2*)(out + ((size_t)node << 7) + (lane << 1)) = r;
}

// ---------------- fused dual GEMM + bias + relu ----------------
// out[i] = relu(A0[i]@W0 + A1[i]@W1 + bias), all K=128, N=128.
// Block: 256 threads, tile 64 nodes x 128 cols, 4x8 acc per thread.
__global__ __launch_bounds__(256) void dual_gemm_bias_relu(
        const float* __restrict__ A0, const float* __restrict__ A1,
        const float* __restrict__ W0, const float* __restrict__ W1,
        const float* __restrict__ bias, float* __restrict__ out, int n, int relu) {
    __shared__ __align__(16) float At[16][68];   // [k][m], padded (272B row stride, 16B aligned)
    __shared__ __align__(16) float Bt[16][128];  // [k][o]
    int tid = threadIdx.x;
    int mi = tid & 15, ni = tid >> 4;
    int m_base = blockIdx.x * 64;
    float acc[4][8];
#pragma unroll
    for (int m = 0; m < 4; ++m)
#pragma unroll
        for (int o = 0; o < 8; ++o) acc[m][o] = 0.f;

#pragma unroll
    for (int pass = 0; pass < 2; ++pass) {
        const float* A = pass ? A1 : A0;
        const float* W = pass ? W1 : W0;
        for (int k0 = 0; k0 < 128; k0 += 16) {
            {   // stage A chunk: 64 m x 16 k (transposed into LDS)
                int m = tid >> 2, kq = (tid & 3) << 2;
                int gm = m_base + m;
                float4 v = make_float4(0.f, 0.f, 0.f, 0.f);
                if (gm < n) v = *(const float4*)(A + ((size_t)gm << 7) + k0 + kq);
                At[kq + 0][m] = v.x;
                At[kq + 1][m] = v.y;
                At[kq + 2][m] = v.z;
                At[kq + 3][m] = v.w;
            }
            {   // stage B chunk: 16 k x 128 o
                int k = tid >> 4, o = (tid & 15) << 3;
                const float* wr = W + ((size_t)(k0 + k) << 7) + o;
                *(float4*)&Bt[k][o] = *(const float4*)(wr);
                *(float4*)&Bt[k][o + 4] = *(const float4*)(wr + 4);
            }
            __syncthreads();
#pragma unroll
            for (int kk = 0; kk < 16; ++kk) {
                float4 a = *(const float4*)&At[kk][mi << 2];
                float4 b0 = *(const float4*)&Bt[kk][ni << 3];
                float4 b1 = *(const float4*)&Bt[kk][(ni << 3) + 4];
                float av[4] = {a.x, a.y, a.z, a.w};
                float bv[8] = {b0.x, b0.y, b0.z, b0.w, b1.x, b1.y, b1.z, b1.w};
#pragma unroll
                for (int m = 0; m < 4; ++m)
#pragma unroll
                    for (int o = 0; o < 8; ++o) acc[m][o] += av[m] * bv[o];
            }
            __syncthreads();
        }
    }
    // epilogue
    int ob = ni << 3;
    float4 bs0 = *(const float4*)(bias + ob);
    float4 bs1 = *(const float4*)(bias + ob + 4);
#pragma unroll
    for (int m = 0; m < 4; ++m) {
        int gm = m_base + (mi << 2) + m;
        if (gm >= n) continue;
        float4 r0, r1;
        r0.x = acc[m][0] + bs0.x;
        r0.y = acc[m][1] + bs0.y;
        r0.z = acc[m][2] + bs0.z;
        r0.w = acc[m][3] + bs0.w;
        r1.x = acc[m][4] + bs1.x;
        r1.y = acc[m][5] + bs1.y;
        r1.z = acc[m][6] + bs1.z;
        r1.w = acc[m][7] + bs1.w;
        if (relu) {
            r0.x = fmaxf(r0.x, 0.f); r0.y = fmaxf(r0.y, 0.f);
            r0.z = fmaxf(r0.z, 0.f); r0.w = fmaxf(r0.w, 0.f);
            r1.x = fmaxf(r1.x, 0.f); r1.y = fmaxf(r1.y, 0.f);
            r1.z = fmaxf(r1.z, 0.f); r1.w = fmaxf(r1.w, 0.f);
        }
        *(float4*)(out + ((size_t)gm << 7) + ob) = r0;
        *(float4*)(out + ((size_t)gm << 7) + ob + 4) = r1;
    }
}

// ---------------- final FC (128 -> 2) ----------------
// one wave per node, shuffle reduction
__global__ __launch_bounds__(256) void fc_kernel(const float* __restrict__ h,
                                                 const float* __restrict__ Wfc,
                                                 const float* __restrict__ bfc,
                                                 float* __restrict__ out, int n) {
    int node = blockIdx.x * 4 + (threadIdx.x >> 6);
    if (node >= n) return;
    int lane = threadIdx.x & 63;
    float2 hv = *(const float2*)(h + ((size_t)node << 7) + (lane << 1));
    float4 w = *(const float4*)(Wfc + (lane << 2));   // Wfc[2l][0..1], Wfc[2l+1][0..1]
    float p0 = hv.x * w.x + hv.y * w.z;
    float p1 = hv.x * w.y + hv.y * w.w;
#pragma unroll
    for (int off = 32; off > 0; off >>= 1) {
        p0 += __shfl_down(p0, off);
        p1 += __shfl_down(p1, off);
    }
    if (lane == 0) {
        out[node * 2 + 0] = p0 + bfc[0];
        out[node * 2 + 1] = p1 + bfc[1];
    }
}

extern "C" void kernel_launch(void* const* d_in, const int* in_sizes, int n_in,
                              void* d_out, int out_size, void* d_ws, size_t ws_size,
                              hipStream_t stream) {
    const float* x   = (const float*)d_in[0];
    const int* edge  = (const int*)d_in[1];
    const float* W1l = (const float*)d_in[2];
    const float* W1r = (const float*)d_in[3];
    const float* b1  = (const float*)d_in[4];
    const float* W2l = (const float*)d_in[5];
    const float* W2r = (const float*)d_in[6];
    const float* b2  = (const float*)d_in[7];
    const float* Wfc = (const float*)d_in[8];
    const float* bfc = (const float*)d_in[9];
    float* out = (float*)d_out;

    const int n = NN, ne = NE;
    const int* src = edge;        // edge_index[0]
    const int* dst = edge + ne;   // edge_index[1]

    char* ws = (char*)d_ws;
    size_t off = 0;
    auto alloc = [&](size_t bytes) -> char* {
        char* p = ws + off;
        off = (off + bytes + 511) & ~(size_t)511;
        return p;
    };
    int* deg      = (int*)alloc((size_t)n * 4);
    int* fill     = (int*)alloc((size_t)n * 4);
    int* row_ptr  = (int*)alloc((size_t)(n + 1) * 4);
    float* invdeg = (float*)alloc((size_t)n * 4);
    int* col      = (int*)alloc((size_t)ne * 4);
    float* agg    = (float*)alloc((size_t)n * 128 * 4);
    float* h1     = (float*)alloc((size_t)n * 128 * 4);
    float* h2     = (float*)alloc((size_t)n * 128 * 4);
    (void)ws_size; (void)in_sizes; (void)n_in; (void)out_size;

    // zero deg + fill (contiguous at front of ws); ws is poisoned 0xAA each call
    hipMemsetAsync(d_ws, 0, (size_t)((char*)row_ptr - (char*)d_ws), stream);

    hist_kernel<<<(ne + 255) / 256, 256, 0, stream>>>(dst, deg, ne);
    scan_kernel<<<1, 1024, 0, stream>>>(deg, row_ptr, invdeg, n);
    fill_kernel<<<(ne + 255) / 256, 256, 0, stream>>>(src, dst, row_ptr, fill, col, ne);

    agg_kernel<<<(n + 3) / 4, 256, 0, stream>>>(x, row_ptr, col, invdeg, agg, n);
    dual_gemm_bias_relu<<<(n + 63) / 64, 256, 0, stream>>>(agg, x, W1l, W1r, b1, h1, n, 1);
    agg_kernel<<<(n + 3) / 4, 256, 0, stream>>>(h1, row_ptr, col, invdeg, agg, n);
    dual_gemm_bias_relu<<<(n + 63) / 64, 256, 0, stream>>>(agg, h1, W2l, W2r, b2, h2, n, 1);
    fc_kernel<<<(n + 3) / 4, 256, 0, stream>>>(h2, Wfc, bfc, out, n);
}

// Round 2
// 452.958 us; speedup vs baseline: 1.2052x; 1.2052x over previous
//
#include <hip/hip_runtime.h>

#define NN 50000
#define NE 800000
#define SCAN_B 256          // elements per scan block
#define SCAN_NB ((NN + SCAN_B - 1) / SCAN_B)   // 196

// ---------------- CSR build ----------------
__global__ void hist_kernel(const int* __restrict__ dst, int* __restrict__ deg, int ne) {
    int e = blockIdx.x * blockDim.x + threadIdx.x;
    if (e < ne) atomicAdd(&deg[dst[e]], 1);
}

// stage 1: per-block sums of deg
__global__ __launch_bounds__(SCAN_B) void block_sum_kernel(const int* __restrict__ deg,
                                                           int* __restrict__ bsum, int n) {
    __shared__ int s[SCAN_B];
    int i = blockIdx.x * SCAN_B + threadIdx.x;
    int v = (i < n) ? deg[i] : 0;
    s[threadIdx.x] = v;
    __syncthreads();
    for (int d = SCAN_B >> 1; d > 0; d >>= 1) {
        if (threadIdx.x < d) s[threadIdx.x] += s[threadIdx.x + d];
        __syncthreads();
    }
    if (threadIdx.x == 0) bsum[blockIdx.x] = s[0];
}

// stage 2: inclusive scan of the block sums (single small block)
__global__ __launch_bounds__(SCAN_B) void scan_bsums_kernel(int* __restrict__ bsum, int nb) {
    __shared__ int s[SCAN_B];
    int t = threadIdx.x;
    s[t] = (t < nb) ? bsum[t] : 0;
    __syncthreads();
    for (int d = 1; d < SCAN_B; d <<= 1) {
        int v = (t >= d) ? s[t - d] : 0;
        __syncthreads();
        s[t] += v;
        __syncthreads();
    }
    if (t < nb) bsum[t] = s[t];   // inclusive
}

// stage 3: per-block exclusive scan + add carried base; emit row_ptr & inv_deg
__global__ __launch_bounds__(SCAN_B) void scatter_scan_kernel(const int* __restrict__ deg,
                                                              const int* __restrict__ bsum,
                                                              int* __restrict__ row_ptr,
                                                              float* __restrict__ inv_deg,
                                                              int n, int ne) {
    __shared__ int s[SCAN_B];
    int t = threadIdx.x;
    int i = blockIdx.x * SCAN_B + t;
    int v = (i < n) ? deg[i] : 0;
    s[t] = v;
    __syncthreads();
    for (int d = 1; d < SCAN_B; d <<= 1) {
        int u = (t >= d) ? s[t - d] : 0;
        __syncthreads();
        s[t] += u;
        __syncthreads();
    }
    int base = (blockIdx.x == 0) ? 0 : bsum[blockIdx.x - 1];
    if (i < n) {
        row_ptr[i] = base + s[t] - v;   // exclusive
        inv_deg[i] = 1.0f / (float)(v > 0 ? v : 1);
    }
    if (blockIdx.x == 0 && t == 0) row_ptr[n] = ne;
}

__global__ void fill_kernel(const int* __restrict__ src, const int* __restrict__ dst,
                            const int* __restrict__ row_ptr, int* __restrict__ fill,
                            int* __restrict__ col, int ne) {
    int e = blockIdx.x * blockDim.x + threadIdx.x;
    if (e >= ne) return;
    int d = dst[e];
    int pos = atomicAdd(&fill[d], 1);
    col[row_ptr[d] + pos] = src[e];
}

// ---------------- mean aggregation (gather over CSR) ----------------
// one 64-lane wave per node; lane handles 2 features (float2, 8B coalesced)
__global__ __launch_bounds__(256) void agg_kernel(const float* __restrict__ h,
                                                  const int* __restrict__ row_ptr,
                                                  const int* __restrict__ col,
                                                  const float* __restrict__ inv_deg,
                                                  float* __restrict__ out, int n) {
    int node = blockIdx.x * 4 + (threadIdx.x >> 6);
    if (node >= n) return;
    int lane = threadIdx.x & 63;
    int beg = row_ptr[node], end = row_ptr[node + 1];
    float ax = 0.f, ay = 0.f;
    for (int e = beg; e < end; ++e) {
        int j = col[e];                                  // wave-uniform
        float2 v = *(const float2*)(h + ((size_t)j << 7) + (lane << 1));
        ax += v.x;
        ay += v.y;
    }
    float s = inv_deg[node];
    float2 r;
    r.x = ax * s;
    r.y = ay * s;
    *(float2*)(out + ((size_t)node << 7) + (lane << 1)) = r;
}

// ---------------- fused dual GEMM + bias + relu ----------------
// out[i] = relu(A0[i]@W0 + A1[i]@W1 + bias), all K=128, N=128.
// Block: 256 threads, tile 64 nodes x 128 cols, 4x8 acc per thread.
__global__ __launch_bounds__(256) void dual_gemm_bias_relu(
        const float* __restrict__ A0, const float* __restrict__ A1,
        const float* __restrict__ W0, const float* __restrict__ W1,
        const float* __restrict__ bias, float* __restrict__ out, int n, int relu) {
    __shared__ __align__(16) float At[16][68];   // [k][m], padded
    __shared__ __align__(16) float Bt[16][128];  // [k][o]
    int tid = threadIdx.x;
    int mi = tid & 15, ni = tid >> 4;
    int m_base = blockIdx.x * 64;
    float acc[4][8];
#pragma unroll
    for (int m = 0; m < 4; ++m)
#pragma unroll
        for (int o = 0; o < 8; ++o) acc[m][o] = 0.f;

#pragma unroll
    for (int pass = 0; pass < 2; ++pass) {
        const float* A = pass ? A1 : A0;
        const float* W = pass ? W1 : W0;
        for (int k0 = 0; k0 < 128; k0 += 16) {
            {   // stage A chunk: 64 m x 16 k (transposed into LDS)
                int m = tid >> 2, kq = (tid & 3) << 2;
                int gm = m_base + m;
                float4 v = make_float4(0.f, 0.f, 0.f, 0.f);
                if (gm < n) v = *(const float4*)(A + ((size_t)gm << 7) + k0 + kq);
                At[kq + 0][m] = v.x;
                At[kq + 1][m] = v.y;
                At[kq + 2][m] = v.z;
                At[kq + 3][m] = v.w;
            }
            {   // stage B chunk: 16 k x 128 o
                int k = tid >> 4, o = (tid & 15) << 3;
                const float* wr = W + ((size_t)(k0 + k) << 7) + o;
                *(float4*)&Bt[k][o] = *(const float4*)(wr);
                *(float4*)&Bt[k][o + 4] = *(const float4*)(wr + 4);
            }
            __syncthreads();
#pragma unroll
            for (int kk = 0; kk < 16; ++kk) {
                float4 a = *(const float4*)&At[kk][mi << 2];
                float4 b0 = *(const float4*)&Bt[kk][ni << 3];
                float4 b1 = *(const float4*)&Bt[kk][(ni << 3) + 4];
                float av[4] = {a.x, a.y, a.z, a.w};
                float bv[8] = {b0.x, b0.y, b0.z, b0.w, b1.x, b1.y, b1.z, b1.w};
#pragma unroll
                for (int m = 0; m < 4; ++m)
#pragma unroll
                    for (int o = 0; o < 8; ++o) acc[m][o] += av[m] * bv[o];
            }
            __syncthreads();
        }
    }
    // epilogue
    int ob = ni << 3;
    float4 bs0 = *(const float4*)(bias + ob);
    float4 bs1 = *(const float4*)(bias + ob + 4);
#pragma unroll
    for (int m = 0; m < 4; ++m) {
        int gm = m_base + (mi << 2) + m;
        if (gm >= n) continue;
        float4 r0, r1;
        r0.x = acc[m][0] + bs0.x;
        r0.y = acc[m][1] + bs0.y;
        r0.z = acc[m][2] + bs0.z;
        r0.w = acc[m][3] + bs0.w;
        r1.x = acc[m][4] + bs1.x;
        r1.y = acc[m][5] + bs1.y;
        r1.z = acc[m][6] + bs1.z;
        r1.w = acc[m][7] + bs1.w;
        if (relu) {
            r0.x = fmaxf(r0.x, 0.f); r0.y = fmaxf(r0.y, 0.f);
            r0.z = fmaxf(r0.z, 0.f); r0.w = fmaxf(r0.w, 0.f);
            r1.x = fmaxf(r1.x, 0.f); r1.y = fmaxf(r1.y, 0.f);
            r1.z = fmaxf(r1.z, 0.f); r1.w = fmaxf(r1.w, 0.f);
        }
        *(float4*)(out + ((size_t)gm << 7) + ob) = r0;
        *(float4*)(out + ((size_t)gm << 7) + ob + 4) = r1;
    }
}

// ---------------- final FC (128 -> 2) ----------------
__global__ __launch_bounds__(256) void fc_kernel(const float* __restrict__ h,
                                                 const float* __restrict__ Wfc,
                                                 const float* __restrict__ bfc,
                                                 float* __restrict__ out, int n) {
    int node = blockIdx.x * 4 + (threadIdx.x >> 6);
    if (node >= n) return;
    int lane = threadIdx.x & 63;
    float2 hv = *(const float2*)(h + ((size_t)node << 7) + (lane << 1));
    float4 w = *(const float4*)(Wfc + (lane << 2));
    float p0 = hv.x * w.x + hv.y * w.z;
    float p1 = hv.x * w.y + hv.y * w.w;
#pragma unroll
    for (int off = 32; off > 0; off >>= 1) {
        p0 += __shfl_down(p0, off);
        p1 += __shfl_down(p1, off);
    }
    if (lane == 0) {
        out[node * 2 + 0] = p0 + bfc[0];
        out[node * 2 + 1] = p1 + bfc[1];
    }
}

extern "C" void kernel_launch(void* const* d_in, const int* in_sizes, int n_in,
                              void* d_out, int out_size, void* d_ws, size_t ws_size,
                              hipStream_t stream) {
    const float* x   = (const float*)d_in[0];
    const int* edge  = (const int*)d_in[1];
    const float* W1l = (const float*)d_in[2];
    const float* W1r = (const float*)d_in[3];
    const float* b1  = (const float*)d_in[4];
    const float* W2l = (const float*)d_in[5];
    const float* W2r = (const float*)d_in[6];
    const float* b2  = (const float*)d_in[7];
    const float* Wfc = (const float*)d_in[8];
    const float* bfc = (const float*)d_in[9];
    float* out = (float*)d_out;

    const int n = NN, ne = NE;
    const int* src = edge;        // edge_index[0]
    const int* dst = edge + ne;   // edge_index[1]

    char* ws = (char*)d_ws;
    size_t off = 0;
    auto alloc = [&](size_t bytes) -> char* {
        char* p = ws + off;
        off = (off + bytes + 511) & ~(size_t)511;
        return p;
    };
    int* deg      = (int*)alloc((size_t)n * 4);
    int* fill     = (int*)alloc((size_t)n * 4);
    int* row_ptr  = (int*)alloc((size_t)(n + 1) * 4);
    float* invdeg = (float*)alloc((size_t)n * 4);
    int* bsum     = (int*)alloc((size_t)SCAN_NB * 4);
    int* col      = (int*)alloc((size_t)ne * 4);
    float* agg    = (float*)alloc((size_t)n * 128 * 4);
    float* h1     = (float*)alloc((size_t)n * 128 * 4);
    float* h2     = (float*)alloc((size_t)n * 128 * 4);
    (void)ws_size; (void)in_sizes; (void)n_in; (void)out_size;

    // zero deg + fill (contiguous at front of ws)
    hipMemsetAsync(d_ws, 0, (size_t)((char*)row_ptr - (char*)d_ws), stream);

    hist_kernel<<<(ne + 255) / 256, 256, 0, stream>>>(dst, deg, ne);
    block_sum_kernel<<<SCAN_NB, SCAN_B, 0, stream>>>(deg, bsum, n);
    scan_bsums_kernel<<<1, SCAN_B, 0, stream>>>(bsum, SCAN_NB);
    scatter_scan_kernel<<<SCAN_NB, SCAN_B, 0, stream>>>(deg, bsum, row_ptr, invdeg, n, ne);
    fill_kernel<<<(ne + 255) / 256, 256, 0, stream>>>(src, dst, row_ptr, fill, col, ne);

    agg_kernel<<<(n + 3) / 4, 256, 0, stream>>>(x, row_ptr, col, invdeg, agg, n);
    dual_gemm_bias_relu<<<(n + 63) / 64, 256, 0, stream>>>(agg, x, W1l, W1r, b1, h1, n, 1);
    agg_kernel<<<(n + 3) / 4, 256, 0, stream>>>(h1, row_ptr, col, invdeg, agg, n);
    dual_gemm_bias_relu<<<(n + 63) / 64, 256, 0, stream>>>(agg, h1, W2l, W2r, b2, h2, n, 1);
    fc_kernel<<<(n + 3) / 4, 256, 0, stream>>>(h2, Wfc, bfc, out, n);
}

// Round 3
// 391.729 us; speedup vs baseline: 1.3936x; 1.1563x over previous
//
#include <hip/hip_runtime.h>

#define NN 50000
#define NE 800000
#define SCAN_B 256          // elements per scan block
#define SCAN_NB ((NN + SCAN_B - 1) / SCAN_B)   // 196

// ---------------- CSR build ----------------
__global__ void hist_kernel(const int* __restrict__ dst, int* __restrict__ deg, int ne) {
    int e = blockIdx.x * blockDim.x + threadIdx.x;
    if (e < ne) atomicAdd(&deg[dst[e]], 1);
}

// stage 1: per-block sums of deg
__global__ __launch_bounds__(SCAN_B) void block_sum_kernel(const int* __restrict__ deg,
                                                           int* __restrict__ bsum, int n) {
    __shared__ int s[SCAN_B];
    int i = blockIdx.x * SCAN_B + threadIdx.x;
    int v = (i < n) ? deg[i] : 0;
    s[threadIdx.x] = v;
    __syncthreads();
    for (int d = SCAN_B >> 1; d > 0; d >>= 1) {
        if (threadIdx.x < d) s[threadIdx.x] += s[threadIdx.x + d];
        __syncthreads();
    }
    if (threadIdx.x == 0) bsum[blockIdx.x] = s[0];
}

// stage 2: inclusive scan of the block sums (single small block)
__global__ __launch_bounds__(SCAN_B) void scan_bsums_kernel(int* __restrict__ bsum, int nb) {
    __shared__ int s[SCAN_B];
    int t = threadIdx.x;
    s[t] = (t < nb) ? bsum[t] : 0;
    __syncthreads();
    for (int d = 1; d < SCAN_B; d <<= 1) {
        int v = (t >= d) ? s[t - d] : 0;
        __syncthreads();
        s[t] += v;
        __syncthreads();
    }
    if (t < nb) bsum[t] = s[t];   // inclusive
}

// stage 3: per-block exclusive scan + add carried base; emit row_ptr & inv_deg
__global__ __launch_bounds__(SCAN_B) void scatter_scan_kernel(const int* __restrict__ deg,
                                                              const int* __restrict__ bsum,
                                                              int* __restrict__ row_ptr,
                                                              float* __restrict__ inv_deg,
                                                              int n, int ne) {
    __shared__ int s[SCAN_B];
    int t = threadIdx.x;
    int i = blockIdx.x * SCAN_B + t;
    int v = (i < n) ? deg[i] : 0;
    s[t] = v;
    __syncthreads();
    for (int d = 1; d < SCAN_B; d <<= 1) {
        int u = (t >= d) ? s[t - d] : 0;
        __syncthreads();
        s[t] += u;
        __syncthreads();
    }
    int base = (blockIdx.x == 0) ? 0 : bsum[blockIdx.x - 1];
    if (i < n) {
        row_ptr[i] = base + s[t] - v;   // exclusive
        inv_deg[i] = 1.0f / (float)(v > 0 ? v : 1);
    }
    if (blockIdx.x == 0 && t == 0) row_ptr[n] = ne;
}

__global__ void fill_kernel(const int* __restrict__ src, const int* __restrict__ dst,
                            const int* __restrict__ row_ptr, int* __restrict__ fill,
                            int* __restrict__ col, int ne) {
    int e = blockIdx.x * blockDim.x + threadIdx.x;
    if (e >= ne) return;
    int d = dst[e];
    int pos = atomicAdd(&fill[d], 1);
    col[row_ptr[d] + pos] = src[e];
}

// ---------------- mean aggregation (gather over CSR) ----------------
// one 64-lane wave per node; lane handles 2 features (float2, 8B coalesced).
// Edge loop unrolled x4 with independent accumulators -> 4 row-loads in
// flight per wave (latency-bound fix; VGPRs were 8, plenty of headroom).
__global__ __launch_bounds__(256) void agg_kernel(const float* __restrict__ h,
                                                  const int* __restrict__ row_ptr,
                                                  const int* __restrict__ col,
                                                  const float* __restrict__ inv_deg,
                                                  float* __restrict__ out, int n) {
    int node = blockIdx.x * 4 + (threadIdx.x >> 6);
    if (node >= n) return;
    int lane = threadIdx.x & 63;
    int beg = row_ptr[node], end = row_ptr[node + 1];
    const float* hl = h + (lane << 1);
    float ax0 = 0.f, ay0 = 0.f, ax1 = 0.f, ay1 = 0.f;
    float ax2 = 0.f, ay2 = 0.f, ax3 = 0.f, ay3 = 0.f;
    int e = beg;
    for (; e + 4 <= end; e += 4) {
        int j0 = col[e + 0];
        int j1 = col[e + 1];
        int j2 = col[e + 2];
        int j3 = col[e + 3];
        float2 v0 = *(const float2*)(hl + ((size_t)j0 << 7));
        float2 v1 = *(const float2*)(hl + ((size_t)j1 << 7));
        float2 v2 = *(const float2*)(hl + ((size_t)j2 << 7));
        float2 v3 = *(const float2*)(hl + ((size_t)j3 << 7));
        ax0 += v0.x; ay0 += v0.y;
        ax1 += v1.x; ay1 += v1.y;
        ax2 += v2.x; ay2 += v2.y;
        ax3 += v3.x; ay3 += v3.y;
    }
    for (; e < end; ++e) {
        int j = col[e];
        float2 v = *(const float2*)(hl + ((size_t)j << 7));
        ax0 += v.x; ay0 += v.y;
    }
    float s = inv_deg[node];
    float2 r;
    r.x = ((ax0 + ax1) + (ax2 + ax3)) * s;
    r.y = ((ay0 + ay1) + (ay2 + ay3)) * s;
    *(float2*)(out + ((size_t)node << 7) + (lane << 1)) = r;
}

// ---------------- fused dual GEMM + bias + relu ----------------
// out[i] = relu(A0[i]@W0 + A1[i]@W1 + bias), all K=128, N=128.
// Block: 256 threads, tile 64 nodes x 128 cols, 4x8 acc per thread.
__global__ __launch_bounds__(256) void dual_gemm_bias_relu(
        const float* __restrict__ A0, const float* __restrict__ A1,
        const float* __restrict__ W0, const float* __restrict__ W1,
        const float* __restrict__ bias, float* __restrict__ out, int n, int relu) {
    __shared__ __align__(16) float At[16][68];   // [k][m], padded
    __shared__ __align__(16) float Bt[16][128];  // [k][o]
    int tid = threadIdx.x;
    int mi = tid & 15, ni = tid >> 4;
    int m_base = blockIdx.x * 64;
    float acc[4][8];
#pragma unroll
    for (int m = 0; m < 4; ++m)
#pragma unroll
        for (int o = 0; o < 8; ++o) acc[m][o] = 0.f;

#pragma unroll
    for (int pass = 0; pass < 2; ++pass) {
        const float* A = pass ? A1 : A0;
        const float* W = pass ? W1 : W0;
        for (int k0 = 0; k0 < 128; k0 += 16) {
            {   // stage A chunk: 64 m x 16 k (transposed into LDS)
                int m = tid >> 2, kq = (tid & 3) << 2;
                int gm = m_base + m;
                float4 v = make_float4(0.f, 0.f, 0.f, 0.f);
                if (gm < n) v = *(const float4*)(A + ((size_t)gm << 7) + k0 + kq);
                At[kq + 0][m] = v.x;
                At[kq + 1][m] = v.y;
                At[kq + 2][m] = v.z;
                At[kq + 3][m] = v.w;
            }
            {   // stage B chunk: 16 k x 128 o
                int k = tid >> 4, o = (tid & 15) << 3;
                const float* wr = W + ((size_t)(k0 + k) << 7) + o;
                *(float4*)&Bt[k][o] = *(const float4*)(wr);
                *(float4*)&Bt[k][o + 4] = *(const float4*)(wr + 4);
            }
            __syncthreads();
#pragma unroll
            for (int kk = 0; kk < 16; ++kk) {
                float4 a = *(const float4*)&At[kk][mi << 2];
                float4 b0 = *(const float4*)&Bt[kk][ni << 3];
                float4 b1 = *(const float4*)&Bt[kk][(ni << 3) + 4];
                float av[4] = {a.x, a.y, a.z, a.w};
                float bv[8] = {b0.x, b0.y, b0.z, b0.w, b1.x, b1.y, b1.z, b1.w};
#pragma unroll
                for (int m = 0; m < 4; ++m)
#pragma unroll
                    for (int o = 0; o < 8; ++o) acc[m][o] += av[m] * bv[o];
            }
            __syncthreads();
        }
    }
    // epilogue
    int ob = ni << 3;
    float4 bs0 = *(const float4*)(bias + ob);
    float4 bs1 = *(const float4*)(bias + ob + 4);
#pragma unroll
    for (int m = 0; m < 4; ++m) {
        int gm = m_base + (mi << 2) + m;
        if (gm >= n) continue;
        float4 r0, r1;
        r0.x = acc[m][0] + bs0.x;
        r0.y = acc[m][1] + bs0.y;
        r0.z = acc[m][2] + bs0.z;
        r0.w = acc[m][3] + bs0.w;
        r1.x = acc[m][4] + bs1.x;
        r1.y = acc[m][5] + bs1.y;
        r1.z = acc[m][6] + bs1.z;
        r1.w = acc[m][7] + bs1.w;
        if (relu) {
            r0.x = fmaxf(r0.x, 0.f); r0.y = fmaxf(r0.y, 0.f);
            r0.z = fmaxf(r0.z, 0.f); r0.w = fmaxf(r0.w, 0.f);
            r1.x = fmaxf(r1.x, 0.f); r1.y = fmaxf(r1.y, 0.f);
            r1.z = fmaxf(r1.z, 0.f); r1.w = fmaxf(r1.w, 0.f);
        }
        *(float4*)(out + ((size_t)gm << 7) + ob) = r0;
        *(float4*)(out + ((size_t)gm << 7) + ob + 4) = r1;
    }
}

// ---------------- final FC (128 -> 2) ----------------
__global__ __launch_bounds__(256) void fc_kernel(const float* __restrict__ h,
                                                 const float* __restrict__ Wfc,
                                                 const float* __restrict__ bfc,
                                                 float* __restrict__ out, int n) {
    int node = blockIdx.x * 4 + (threadIdx.x >> 6);
    if (node >= n) return;
    int lane = threadIdx.x & 63;
    float2 hv = *(const float2*)(h + ((size_t)node << 7) + (lane << 1));
    float4 w = *(const float4*)(Wfc + (lane << 2));
    float p0 = hv.x * w.x + hv.y * w.z;
    float p1 = hv.x * w.y + hv.y * w.w;
#pragma unroll
    for (int off = 32; off > 0; off >>= 1) {
        p0 += __shfl_down(p0, off);
        p1 += __shfl_down(p1, off);
    }
    if (lane == 0) {
        out[node * 2 + 0] = p0 + bfc[0];
        out[node * 2 + 1] = p1 + bfc[1];
    }
}

extern "C" void kernel_launch(void* const* d_in, const int* in_sizes, int n_in,
                              void* d_out, int out_size, void* d_ws, size_t ws_size,
                              hipStream_t stream) {
    const float* x   = (const float*)d_in[0];
    const int* edge  = (const int*)d_in[1];
    const float* W1l = (const float*)d_in[2];
    const float* W1r = (const float*)d_in[3];
    const float* b1  = (const float*)d_in[4];
    const float* W2l = (const float*)d_in[5];
    const float* W2r = (const float*)d_in[6];
    const float* b2  = (const float*)d_in[7];
    const float* Wfc = (const float*)d_in[8];
    const float* bfc = (const float*)d_in[9];
    float* out = (float*)d_out;

    const int n = NN, ne = NE;
    const int* src = edge;        // edge_index[0]
    const int* dst = edge + ne;   // edge_index[1]

    char* ws = (char*)d_ws;
    size_t off = 0;
    auto alloc = [&](size_t bytes) -> char* {
        char* p = ws + off;
        off = (off + bytes + 511) & ~(size_t)511;
        return p;
    };
    int* deg      = (int*)alloc((size_t)n * 4);
    int* fill     = (int*)alloc((size_t)n * 4);
    int* row_ptr  = (int*)alloc((size_t)(n + 1) * 4);
    float* invdeg = (float*)alloc((size_t)n * 4);
    int* bsum     = (int*)alloc((size_t)SCAN_NB * 4);
    int* col      = (int*)alloc((size_t)ne * 4);
    float* agg    = (float*)alloc((size_t)n * 128 * 4);
    float* h1     = (float*)alloc((size_t)n * 128 * 4);
    float* h2     = (float*)alloc((size_t)n * 128 * 4);
    (void)ws_size; (void)in_sizes; (void)n_in; (void)out_size;

    // zero deg + fill (contiguous at front of ws)
    hipMemsetAsync(d_ws, 0, (size_t)((char*)row_ptr - (char*)d_ws), stream);

    hist_kernel<<<(ne + 255) / 256, 256, 0, stream>>>(dst, deg, ne);
    block_sum_kernel<<<SCAN_NB, SCAN_B, 0, stream>>>(deg, bsum, n);
    scan_bsums_kernel<<<1, SCAN_B, 0, stream>>>(bsum, SCAN_NB);
    scatter_scan_kernel<<<SCAN_NB, SCAN_B, 0, stream>>>(deg, bsum, row_ptr, invdeg, n, ne);
    fill_kernel<<<(ne + 255) / 256, 256, 0, stream>>>(src, dst, row_ptr, fill, col, ne);

    agg_kernel<<<(n + 3) / 4, 256, 0, stream>>>(x, row_ptr, col, invdeg, agg, n);
    dual_gemm_bias_relu<<<(n + 63) / 64, 256, 0, stream>>>(agg, x, W1l, W1r, b1, h1, n, 1);
    agg_kernel<<<(n + 3) / 4, 256, 0, stream>>>(h1, row_ptr, col, invdeg, agg, n);
    dual_gemm_bias_relu<<<(n + 63) / 64, 256, 0, stream>>>(agg, h1, W2l, W2r, b2, h2, n, 1);
    fc_kernel<<<(n + 3) / 4, 256, 0, stream>>>(h2, Wfc, bfc, out, n);
}

// Round 4
// 343.582 us; speedup vs baseline: 1.5889x; 1.1401x over previous
//
#include <hip/hip_runtime.h>

#define NN 50000
#define NE 800000
#define SCAN_B 256          // elements per scan block
#define SCAN_NB ((NN + SCAN_B - 1) / SCAN_B)   // 196

typedef short short8 __attribute__((ext_vector_type(8)));
typedef float f32x4 __attribute__((ext_vector_type(4)));

__device__ inline unsigned short bf16_rne(float f) {
    unsigned u = __float_as_uint(f);
    unsigned r = (u + 0x7fffu + ((u >> 16) & 1u)) >> 16;
    return (unsigned short)r;
}
__device__ inline float bf16_to_f32(unsigned short h) {
    return __uint_as_float((unsigned)h << 16);
}

// ---------------- CSR build ----------------
__global__ void hist_kernel(const int* __restrict__ dst, int* __restrict__ deg, int ne) {
    int e = blockIdx.x * blockDim.x + threadIdx.x;
    if (e < ne) atomicAdd(&deg[dst[e]], 1);
}

__global__ __launch_bounds__(SCAN_B) void block_sum_kernel(const int* __restrict__ deg,
                                                           int* __restrict__ bsum, int n) {
    __shared__ int s[SCAN_B];
    int i = blockIdx.x * SCAN_B + threadIdx.x;
    int v = (i < n) ? deg[i] : 0;
    s[threadIdx.x] = v;
    __syncthreads();
    for (int d = SCAN_B >> 1; d > 0; d >>= 1) {
        if (threadIdx.x < d) s[threadIdx.x] += s[threadIdx.x + d];
        __syncthreads();
    }
    if (threadIdx.x == 0) bsum[blockIdx.x] = s[0];
}

__global__ __launch_bounds__(SCAN_B) void scan_bsums_kernel(int* __restrict__ bsum, int nb) {
    __shared__ int s[SCAN_B];
    int t = threadIdx.x;
    s[t] = (t < nb) ? bsum[t] : 0;
    __syncthreads();
    for (int d = 1; d < SCAN_B; d <<= 1) {
        int v = (t >= d) ? s[t - d] : 0;
        __syncthreads();
        s[t] += v;
        __syncthreads();
    }
    if (t < nb) bsum[t] = s[t];   // inclusive
}

__global__ __launch_bounds__(SCAN_B) void scatter_scan_kernel(const int* __restrict__ deg,
                                                              const int* __restrict__ bsum,
                                                              int* __restrict__ row_ptr,
                                                              float* __restrict__ inv_deg,
                                                              int n, int ne) {
    __shared__ int s[SCAN_B];
    int t = threadIdx.x;
    int i = blockIdx.x * SCAN_B + t;
    int v = (i < n) ? deg[i] : 0;
    s[t] = v;
    __syncthreads();
    for (int d = 1; d < SCAN_B; d <<= 1) {
        int u = (t >= d) ? s[t - d] : 0;
        __syncthreads();
        s[t] += u;
        __syncthreads();
    }
    int base = (blockIdx.x == 0) ? 0 : bsum[blockIdx.x - 1];
    if (i < n) {
        row_ptr[i] = base + s[t] - v;   // exclusive
        inv_deg[i] = 1.0f / (float)(v > 0 ? v : 1);
    }
    if (blockIdx.x == 0 && t == 0) row_ptr[n] = ne;
}

__global__ void fill_kernel(const int* __restrict__ src, const int* __restrict__ dst,
                            const int* __restrict__ row_ptr, int* __restrict__ fill,
                            int* __restrict__ col, int ne) {
    int e = blockIdx.x * blockDim.x + threadIdx.x;
    if (e >= ne) return;
    int d = dst[e];
    int pos = atomicAdd(&fill[d], 1);
    col[row_ptr[d] + pos] = src[e];
}

// ---------------- weight prep: split fp32 -> (hi,lo) bf16, fragment-ordered ----
// Layout per matrix (32768 shorts): [nt(8)][kc(4)][pl(2)][lane(64)][j(8)]
// frag semantics (16x16x32): B[k][n], n = lane&15, k = kc*32 + (lane>>4)*8 + j
__global__ __launch_bounds__(256) void prep_weights(const float* __restrict__ W0,
                                                    const float* __restrict__ W1,
                                                    const float* __restrict__ W2,
                                                    const float* __restrict__ W3,
                                                    short* __restrict__ wf) {
    int t = blockIdx.x * 256 + threadIdx.x;   // 8192 threads total
    int mat = t >> 11;
    const float* W = (mat == 0) ? W0 : (mat == 1) ? W1 : (mat == 2) ? W2 : W3;
    short* out = wf + (size_t)mat * 32768;
    int r = t & 2047;
    int nt = r >> 8;
    int kc = (r >> 6) & 3;
    int lane = r & 63;
    int n = nt * 16 + (lane & 15);
    int kbase = kc * 32 + ((lane >> 4) << 3);
    short8 vh, vl;
#pragma unroll
    for (int j = 0; j < 8; ++j) {
        float w = W[(size_t)(kbase + j) * 128 + n];
        unsigned short h = bf16_rne(w);
        unsigned short l = bf16_rne(w - bf16_to_f32(h));
        vh[j] = (short)h;
        vl[j] = (short)l;
    }
    size_t o = ((((size_t)nt * 4 + kc) * 2) * 64 + lane) * 8;
    *(short8*)(out + o) = vh;
    *(short8*)(out + o + 512) = vl;   // pl=1 plane is +64*8 shorts
}

// ---------------- mean aggregation (gather over CSR), x8 unrolled ----------------
__global__ __launch_bounds__(256) void agg_kernel(const float* __restrict__ h,
                                                  const int* __restrict__ row_ptr,
                                                  const int* __restrict__ col,
                                                  const float* __restrict__ inv_deg,
                                                  float* __restrict__ out, int n) {
    int node = blockIdx.x * 4 + (threadIdx.x >> 6);
    if (node >= n) return;
    int lane = threadIdx.x & 63;
    int beg = row_ptr[node], end = row_ptr[node + 1];
    const float* hl = h + (lane << 1);
    float ax[8], ay[8];
#pragma unroll
    for (int u = 0; u < 8; ++u) { ax[u] = 0.f; ay[u] = 0.f; }
    int e = beg;
    for (; e + 8 <= end; e += 8) {
        int j[8];
#pragma unroll
        for (int u = 0; u < 8; ++u) j[u] = col[e + u];
        float2 v[8];
#pragma unroll
        for (int u = 0; u < 8; ++u) v[u] = *(const float2*)(hl + ((size_t)j[u] << 7));
#pragma unroll
        for (int u = 0; u < 8; ++u) { ax[u] += v[u].x; ay[u] += v[u].y; }
    }
    for (; e < end; ++e) {
        int j = col[e];
        float2 v = *(const float2*)(hl + ((size_t)j << 7));
        ax[0] += v.x; ay[0] += v.y;
    }
    float sx = ((ax[0] + ax[1]) + (ax[2] + ax[3])) + ((ax[4] + ax[5]) + (ax[6] + ax[7]));
    float sy = ((ay[0] + ay[1]) + (ay[2] + ay[3])) + ((ay[4] + ay[5]) + (ay[6] + ay[7]));
    float s = inv_deg[node];
    float2 r;
    r.x = sx * s;
    r.y = sy * s;
    *(float2*)(out + ((size_t)node << 7) + (lane << 1)) = r;
}

// ---------------- fused dual GEMM via split-bf16 MFMA ----------------
// out[i] = act(A0[i]@W0 + A1[i]@W1 + bias). M-tile 64/block (16/wave), no LDS.
// A fp32 loaded directly as fragments (A[m=lane&15][k=quad*8+j]) and split
// in-register; W pre-split + fragment-ordered by prep_weights.
__global__ __launch_bounds__(256) void gemm_mfma(const float* __restrict__ A0,
                                                 const float* __restrict__ A1,
                                                 const short* __restrict__ Wf0,
                                                 const short* __restrict__ Wf1,
                                                 const float* __restrict__ bias,
                                                 float* __restrict__ out, int n, int relu) {
    int lane = threadIdx.x & 63;
    int wave = threadIdx.x >> 6;
    int quad = lane >> 4, m16 = lane & 15;
    int row_base = blockIdx.x * 64 + wave * 16;
    int arow = row_base + m16;
    if (arow > n - 1) arow = n - 1;            // clamp (padding rows never stored)

    f32x4 acc[8];
#pragma unroll
    for (int nt = 0; nt < 8; ++nt) acc[nt] = (f32x4){0.f, 0.f, 0.f, 0.f};

#pragma unroll
    for (int pass = 0; pass < 2; ++pass) {
        const float* A = pass ? A1 : A0;
        const short* Wf = pass ? Wf1 : Wf0;
        const float* ap = A + ((size_t)arow << 7) + (quad << 3);
#pragma unroll
        for (int kc = 0; kc < 4; ++kc) {
            float4 av0 = *(const float4*)(ap + kc * 32);
            float4 av1 = *(const float4*)(ap + kc * 32 + 4);
            float af[8] = {av0.x, av0.y, av0.z, av0.w, av1.x, av1.y, av1.z, av1.w};
            short8 ah, al;
#pragma unroll
            for (int j = 0; j < 8; ++j) {
                unsigned short h = bf16_rne(af[j]);
                ah[j] = (short)h;
                al[j] = (short)bf16_rne(af[j] - bf16_to_f32(h));
            }
            const short* wp = Wf + ((size_t)kc * 2 * 64 + lane) * 8;
#pragma unroll
            for (int nt = 0; nt < 8; ++nt) {
                short8 bh = *(const short8*)(wp + (size_t)nt * 4096);
                short8 bl = *(const short8*)(wp + (size_t)nt * 4096 + 512);
                acc[nt] = __builtin_amdgcn_mfma_f32_16x16x32_bf16(ah, bh, acc[nt], 0, 0, 0);
                acc[nt] = __builtin_amdgcn_mfma_f32_16x16x32_bf16(al, bh, acc[nt], 0, 0, 0);
                acc[nt] = __builtin_amdgcn_mfma_f32_16x16x32_bf16(ah, bl, acc[nt], 0, 0, 0);
            }
        }
    }

    // epilogue: C/D layout col = lane&15, row = quad*4 + reg
    float bcol[8];
#pragma unroll
    for (int nt = 0; nt < 8; ++nt) bcol[nt] = bias[nt * 16 + m16];
#pragma unroll
    for (int r = 0; r < 4; ++r) {
        int row = row_base + quad * 4 + r;
        if (row >= n) continue;
        float* op = out + ((size_t)row << 7) + m16;
#pragma unroll
        for (int nt = 0; nt < 8; ++nt) {
            float v = acc[nt][r] + bcol[nt];
            if (relu) v = fmaxf(v, 0.f);
            op[nt * 16] = v;
        }
    }
}

// ---------------- final FC (128 -> 2) ----------------
__global__ __launch_bounds__(256) void fc_kernel(const float* __restrict__ h,
                                                 const float* __restrict__ Wfc,
                                                 const float* __restrict__ bfc,
                                                 float* __restrict__ out, int n) {
    int node = blockIdx.x * 4 + (threadIdx.x >> 6);
    if (node >= n) return;
    int lane = threadIdx.x & 63;
    float2 hv = *(const float2*)(h + ((size_t)node << 7) + (lane << 1));
    float4 w = *(const float4*)(Wfc + (lane << 2));
    float p0 = hv.x * w.x + hv.y * w.z;
    float p1 = hv.x * w.y + hv.y * w.w;
#pragma unroll
    for (int off = 32; off > 0; off >>= 1) {
        p0 += __shfl_down(p0, off);
        p1 += __shfl_down(p1, off);
    }
    if (lane == 0) {
        out[node * 2 + 0] = p0 + bfc[0];
        out[node * 2 + 1] = p1 + bfc[1];
    }
}

extern "C" void kernel_launch(void* const* d_in, const int* in_sizes, int n_in,
                              void* d_out, int out_size, void* d_ws, size_t ws_size,
                              hipStream_t stream) {
    const float* x   = (const float*)d_in[0];
    const int* edge  = (const int*)d_in[1];
    const float* W1l = (const float*)d_in[2];
    const float* W1r = (const float*)d_in[3];
    const float* b1  = (const float*)d_in[4];
    const float* W2l = (const float*)d_in[5];
    const float* W2r = (const float*)d_in[6];
    const float* b2  = (const float*)d_in[7];
    const float* Wfc = (const float*)d_in[8];
    const float* bfc = (const float*)d_in[9];
    float* out = (float*)d_out;

    const int n = NN, ne = NE;
    const int* src = edge;        // edge_index[0]
    const int* dst = edge + ne;   // edge_index[1]

    char* ws = (char*)d_ws;
    size_t off = 0;
    auto alloc = [&](size_t bytes) -> char* {
        char* p = ws + off;
        off = (off + bytes + 511) & ~(size_t)511;
        return p;
    };
    int* deg      = (int*)alloc((size_t)n * 4);
    int* fill     = (int*)alloc((size_t)n * 4);
    int* row_ptr  = (int*)alloc((size_t)(n + 1) * 4);
    float* invdeg = (float*)alloc((size_t)n * 4);
    int* bsum     = (int*)alloc((size_t)SCAN_NB * 4);
    short* wf     = (short*)alloc((size_t)4 * 32768 * 2);   // 4 matrices, frag-ordered hi/lo
    int* col      = (int*)alloc((size_t)ne * 4);
    float* agg    = (float*)alloc((size_t)n * 128 * 4);
    float* h1     = (float*)alloc((size_t)n * 128 * 4);
    float* h2     = (float*)alloc((size_t)n * 128 * 4);
    (void)ws_size; (void)in_sizes; (void)n_in; (void)out_size;

    // zero deg + fill (contiguous at front of ws)
    hipMemsetAsync(d_ws, 0, (size_t)((char*)row_ptr - (char*)d_ws), stream);

    hist_kernel<<<(ne + 255) / 256, 256, 0, stream>>>(dst, deg, ne);
    block_sum_kernel<<<SCAN_NB, SCAN_B, 0, stream>>>(deg, bsum, n);
    scan_bsums_kernel<<<1, SCAN_B, 0, stream>>>(bsum, SCAN_NB);
    scatter_scan_kernel<<<SCAN_NB, SCAN_B, 0, stream>>>(deg, bsum, row_ptr, invdeg, n, ne);
    fill_kernel<<<(ne + 255) / 256, 256, 0, stream>>>(src, dst, row_ptr, fill, col, ne);
    prep_weights<<<32, 256, 0, stream>>>(W1l, W1r, W2l, W2r, wf);

    agg_kernel<<<(n + 3) / 4, 256, 0, stream>>>(x, row_ptr, col, invdeg, agg, n);
    gemm_mfma<<<(n + 63) / 64, 256, 0, stream>>>(agg, x, wf, wf + 32768, b1, h1, n, 1);
    agg_kernel<<<(n + 3) / 4, 256, 0, stream>>>(h1, row_ptr, col, invdeg, agg, n);
    gemm_mfma<<<(n + 63) / 64, 256, 0, stream>>>(agg, h1, wf + 2 * 32768, wf + 3 * 32768, b2, h2, n, 1);
    fc_kernel<<<(n + 3) / 4, 256, 0, stream>>>(h2, Wfc, bfc, out, n);
}

// Round 5
// 317.975 us; speedup vs baseline: 1.7169x; 1.0805x over previous
//
#include <hip/hip_runtime.h>

#define NN 50000
#define NE 800000
#define SCAN_B 256          // elements per scan block
#define SCAN_NB ((NN + SCAN_B - 1) / SCAN_B)   // 196

typedef short short8 __attribute__((ext_vector_type(8)));
typedef short short4v __attribute__((ext_vector_type(4)));
typedef float f32x4 __attribute__((ext_vector_type(4)));

__device__ inline unsigned short bf16_rne(float f) {
    unsigned u = __float_as_uint(f);
    unsigned r = (u + 0x7fffu + ((u >> 16) & 1u)) >> 16;
    return (unsigned short)r;
}
__device__ inline float bf16_to_f32(unsigned short h) {
    return __uint_as_float((unsigned)h << 16);
}

// ---------------- CSR build ----------------
__global__ void hist_kernel(const int* __restrict__ dst, int* __restrict__ deg, int ne) {
    int e = blockIdx.x * blockDim.x + threadIdx.x;
    if (e < ne) atomicAdd(&deg[dst[e]], 1);
}

__global__ __launch_bounds__(SCAN_B) void block_sum_kernel(const int* __restrict__ deg,
                                                           int* __restrict__ bsum, int n) {
    __shared__ int s[SCAN_B];
    int i = blockIdx.x * SCAN_B + threadIdx.x;
    int v = (i < n) ? deg[i] : 0;
    s[threadIdx.x] = v;
    __syncthreads();
    for (int d = SCAN_B >> 1; d > 0; d >>= 1) {
        if (threadIdx.x < d) s[threadIdx.x] += s[threadIdx.x + d];
        __syncthreads();
    }
    if (threadIdx.x == 0) bsum[blockIdx.x] = s[0];
}

__global__ __launch_bounds__(SCAN_B) void scan_bsums_kernel(int* __restrict__ bsum, int nb) {
    __shared__ int s[SCAN_B];
    int t = threadIdx.x;
    s[t] = (t < nb) ? bsum[t] : 0;
    __syncthreads();
    for (int d = 1; d < SCAN_B; d <<= 1) {
        int v = (t >= d) ? s[t - d] : 0;
        __syncthreads();
        s[t] += v;
        __syncthreads();
    }
    if (t < nb) bsum[t] = s[t];   // inclusive
}

__global__ __launch_bounds__(SCAN_B) void scatter_scan_kernel(const int* __restrict__ deg,
                                                              const int* __restrict__ bsum,
                                                              int* __restrict__ row_ptr,
                                                              float* __restrict__ inv_deg,
                                                              int n, int ne) {
    __shared__ int s[SCAN_B];
    int t = threadIdx.x;
    int i = blockIdx.x * SCAN_B + t;
    int v = (i < n) ? deg[i] : 0;
    s[t] = v;
    __syncthreads();
    for (int d = 1; d < SCAN_B; d <<= 1) {
        int u = (t >= d) ? s[t - d] : 0;
        __syncthreads();
        s[t] += u;
        __syncthreads();
    }
    int base = (blockIdx.x == 0) ? 0 : bsum[blockIdx.x - 1];
    if (i < n) {
        row_ptr[i] = base + s[t] - v;   // exclusive
        inv_deg[i] = 1.0f / (float)(v > 0 ? v : 1);
    }
    if (blockIdx.x == 0 && t == 0) row_ptr[n] = ne;
}

__global__ void fill_kernel(const int* __restrict__ src, const int* __restrict__ dst,
                            const int* __restrict__ row_ptr, int* __restrict__ fill,
                            int* __restrict__ col, int ne) {
    int e = blockIdx.x * blockDim.x + threadIdx.x;
    if (e >= ne) return;
    int d = dst[e];
    int pos = atomicAdd(&fill[d], 1);
    col[row_ptr[d] + pos] = src[e];
}

// ---------------- fp32 -> bf16 feature convert (for gather) ----------------
__global__ __launch_bounds__(256) void cvt_bf16_kernel(const float* __restrict__ in,
                                                       unsigned short* __restrict__ out, int n4) {
    int i = blockIdx.x * 256 + threadIdx.x;     // one float4 per thread
    if (i >= n4) return;
    float4 v = ((const float4*)in)[i];
    short4v r;
    r[0] = (short)bf16_rne(v.x);
    r[1] = (short)bf16_rne(v.y);
    r[2] = (short)bf16_rne(v.z);
    r[3] = (short)bf16_rne(v.w);
    ((short4v*)out)[i] = r;
}

// ---------------- weight prep: split fp32 -> (hi,lo) bf16, fragment-ordered ----
// Layout per matrix (32768 shorts): [nt(8)][kc(4)][pl(2)][lane(64)][j(8)]
// frag semantics (16x16x32): B[k][n], n = lane&15, k = kc*32 + (lane>>4)*8 + j
__global__ __launch_bounds__(256) void prep_weights(const float* __restrict__ W0,
                                                    const float* __restrict__ W1,
                                                    const float* __restrict__ W2,
                                                    const float* __restrict__ W3,
                                                    short* __restrict__ wf) {
    int t = blockIdx.x * 256 + threadIdx.x;   // 8192 threads total
    int mat = t >> 11;
    const float* W = (mat == 0) ? W0 : (mat == 1) ? W1 : (mat == 2) ? W2 : W3;
    short* out = wf + (size_t)mat * 32768;
    int r = t & 2047;
    int nt = r >> 8;
    int kc = (r >> 6) & 3;
    int lane = r & 63;
    int n = nt * 16 + (lane & 15);
    int kbase = kc * 32 + ((lane >> 4) << 3);
    short8 vh, vl;
#pragma unroll
    for (int j = 0; j < 8; ++j) {
        float w = W[(size_t)(kbase + j) * 128 + n];
        unsigned short h = bf16_rne(w);
        unsigned short l = bf16_rne(w - bf16_to_f32(h));
        vh[j] = (short)h;
        vl[j] = (short)l;
    }
    size_t o = ((((size_t)nt * 4 + kc) * 2) * 64 + lane) * 8;
    *(short8*)(out + o) = vh;
    *(short8*)(out + o + 512) = vl;   // pl=1 plane is +64*8 shorts
}

// ---------------- mean aggregation over bf16 features, fp32 accumulate ------
// one wave per node; lane loads one dword (2 bf16) per row; x8 unrolled
__global__ __launch_bounds__(256) void agg_kernel(const unsigned short* __restrict__ hb,
                                                  const int* __restrict__ row_ptr,
                                                  const int* __restrict__ col,
                                                  const float* __restrict__ inv_deg,
                                                  float* __restrict__ out, int n) {
    int node = blockIdx.x * 4 + (threadIdx.x >> 6);
    if (node >= n) return;
    int lane = threadIdx.x & 63;
    int beg = row_ptr[node], end = row_ptr[node + 1];
    const unsigned short* hl = hb + (lane << 1);
    float ax[8], ay[8];
#pragma unroll
    for (int u = 0; u < 8; ++u) { ax[u] = 0.f; ay[u] = 0.f; }
    int e = beg;
    for (; e + 8 <= end; e += 8) {
        int j[8];
#pragma unroll
        for (int u = 0; u < 8; ++u) j[u] = col[e + u];
        unsigned v[8];
#pragma unroll
        for (int u = 0; u < 8; ++u) v[u] = *(const unsigned*)(hl + ((size_t)j[u] << 7));
#pragma unroll
        for (int u = 0; u < 8; ++u) {
            ax[u] += __uint_as_float(v[u] << 16);
            ay[u] += __uint_as_float(v[u] & 0xffff0000u);
        }
    }
    for (; e < end; ++e) {
        int j = col[e];
        unsigned v = *(const unsigned*)(hl + ((size_t)j << 7));
        ax[0] += __uint_as_float(v << 16);
        ay[0] += __uint_as_float(v & 0xffff0000u);
    }
    float sx = ((ax[0] + ax[1]) + (ax[2] + ax[3])) + ((ax[4] + ax[5]) + (ax[6] + ax[7]));
    float sy = ((ay[0] + ay[1]) + (ay[2] + ay[3])) + ((ay[4] + ay[5]) + (ay[6] + ay[7]));
    float s = inv_deg[node];
    float2 r;
    r.x = sx * s;
    r.y = sy * s;
    *(float2*)(out + ((size_t)node << 7) + (lane << 1)) = r;
}

// ---------------- fused dual GEMM via split-bf16 MFMA ----------------
// out[i] = act(A0[i]@W0 + A1[i]@W1 + bias). M-tile 64/block (16/wave), no LDS.
// Optionally also writes bf16 copy of the output (for next layer's gather).
__global__ __launch_bounds__(256) void gemm_mfma(const float* __restrict__ A0,
                                                 const float* __restrict__ A1,
                                                 const short* __restrict__ Wf0,
                                                 const short* __restrict__ Wf1,
                                                 const float* __restrict__ bias,
                                                 float* __restrict__ out,
                                                 unsigned short* __restrict__ outb,
                                                 int n, int relu) {
    int lane = threadIdx.x & 63;
    int wave = threadIdx.x >> 6;
    int quad = lane >> 4, m16 = lane & 15;
    int row_base = blockIdx.x * 64 + wave * 16;
    int arow = row_base + m16;
    if (arow > n - 1) arow = n - 1;            // clamp (padding rows never stored)

    f32x4 acc[8];
#pragma unroll
    for (int nt = 0; nt < 8; ++nt) acc[nt] = (f32x4){0.f, 0.f, 0.f, 0.f};

#pragma unroll
    for (int pass = 0; pass < 2; ++pass) {
        const float* A = pass ? A1 : A0;
        const short* Wf = pass ? Wf1 : Wf0;
        const float* ap = A + ((size_t)arow << 7) + (quad << 3);
#pragma unroll
        for (int kc = 0; kc < 4; ++kc) {
            float4 av0 = *(const float4*)(ap + kc * 32);
            float4 av1 = *(const float4*)(ap + kc * 32 + 4);
            float af[8] = {av0.x, av0.y, av0.z, av0.w, av1.x, av1.y, av1.z, av1.w};
            short8 ah, al;
#pragma unroll
            for (int j = 0; j < 8; ++j) {
                unsigned short h = bf16_rne(af[j]);
                ah[j] = (short)h;
                al[j] = (short)bf16_rne(af[j] - bf16_to_f32(h));
            }
            const short* wp = Wf + ((size_t)kc * 2 * 64 + lane) * 8;
#pragma unroll
            for (int nt = 0; nt < 8; ++nt) {
                short8 bh = *(const short8*)(wp + (size_t)nt * 4096);
                short8 bl = *(const short8*)(wp + (size_t)nt * 4096 + 512);
                acc[nt] = __builtin_amdgcn_mfma_f32_16x16x32_bf16(ah, bh, acc[nt], 0, 0, 0);
                acc[nt] = __builtin_amdgcn_mfma_f32_16x16x32_bf16(al, bh, acc[nt], 0, 0, 0);
                acc[nt] = __builtin_amdgcn_mfma_f32_16x16x32_bf16(ah, bl, acc[nt], 0, 0, 0);
            }
        }
    }

    // epilogue: C/D layout col = lane&15, row = quad*4 + reg
    float bcol[8];
#pragma unroll
    for (int nt = 0; nt < 8; ++nt) bcol[nt] = bias[nt * 16 + m16];
#pragma unroll
    for (int r = 0; r < 4; ++r) {
        int row = row_base + quad * 4 + r;
        if (row >= n) continue;
        float* op = out + ((size_t)row << 7) + m16;
        unsigned short* opb = outb ? (outb + ((size_t)row << 7) + m16) : (unsigned short*)0;
#pragma unroll
        for (int nt = 0; nt < 8; ++nt) {
            float v = acc[nt][r] + bcol[nt];
            if (relu) v = fmaxf(v, 0.f);
            op[nt * 16] = v;
            if (opb) opb[nt * 16] = bf16_rne(v);
        }
    }
}

// ---------------- final FC (128 -> 2) ----------------
__global__ __launch_bounds__(256) void fc_kernel(const float* __restrict__ h,
                                                 const float* __restrict__ Wfc,
                                                 const float* __restrict__ bfc,
                                                 float* __restrict__ out, int n) {
    int node = blockIdx.x * 4 + (threadIdx.x >> 6);
    if (node >= n) return;
    int lane = threadIdx.x & 63;
    float2 hv = *(const float2*)(h + ((size_t)node << 7) + (lane << 1));
    float4 w = *(const float4*)(Wfc + (lane << 2));
    float p0 = hv.x * w.x + hv.y * w.z;
    float p1 = hv.x * w.y + hv.y * w.w;
#pragma unroll
    for (int off = 32; off > 0; off >>= 1) {
        p0 += __shfl_down(p0, off);
        p1 += __shfl_down(p1, off);
    }
    if (lane == 0) {
        out[node * 2 + 0] = p0 + bfc[0];
        out[node * 2 + 1] = p1 + bfc[1];
    }
}

extern "C" void kernel_launch(void* const* d_in, const int* in_sizes, int n_in,
                              void* d_out, int out_size, void* d_ws, size_t ws_size,
                              hipStream_t stream) {
    const float* x   = (const float*)d_in[0];
    const int* edge  = (const int*)d_in[1];
    const float* W1l = (const float*)d_in[2];
    const float* W1r = (const float*)d_in[3];
    const float* b1  = (const float*)d_in[4];
    const float* W2l = (const float*)d_in[5];
    const float* W2r = (const float*)d_in[6];
    const float* b2  = (const float*)d_in[7];
    const float* Wfc = (const float*)d_in[8];
    const float* bfc = (const float*)d_in[9];
    float* out = (float*)d_out;

    const int n = NN, ne = NE;
    const int* src = edge;        // edge_index[0]
    const int* dst = edge + ne;   // edge_index[1]

    char* ws = (char*)d_ws;
    size_t off = 0;
    auto alloc = [&](size_t bytes) -> char* {
        char* p = ws + off;
        off = (off + bytes + 511) & ~(size_t)511;
        return p;
    };
    int* deg      = (int*)alloc((size_t)n * 4);
    int* fill     = (int*)alloc((size_t)n * 4);
    int* row_ptr  = (int*)alloc((size_t)(n + 1) * 4);
    float* invdeg = (float*)alloc((size_t)n * 4);
    int* bsum     = (int*)alloc((size_t)SCAN_NB * 4);
    short* wf     = (short*)alloc((size_t)4 * 32768 * 2);   // 4 matrices, frag-ordered hi/lo
    int* col      = (int*)alloc((size_t)ne * 4);
    float* agg    = (float*)alloc((size_t)n * 128 * 4);
    float* h1     = (float*)alloc((size_t)n * 128 * 4);
    float* h2     = (float*)alloc((size_t)n * 128 * 4);
    unsigned short* xb  = (unsigned short*)alloc((size_t)n * 128 * 2);  // bf16 x
    unsigned short* h1b = (unsigned short*)alloc((size_t)n * 128 * 2);  // bf16 h1
    (void)ws_size; (void)in_sizes; (void)n_in; (void)out_size;

    // zero deg + fill (contiguous at front of ws)
    hipMemsetAsync(d_ws, 0, (size_t)((char*)row_ptr - (char*)d_ws), stream);

    hist_kernel<<<(ne + 255) / 256, 256, 0, stream>>>(dst, deg, ne);
    block_sum_kernel<<<SCAN_NB, SCAN_B, 0, stream>>>(deg, bsum, n);
    scan_bsums_kernel<<<1, SCAN_B, 0, stream>>>(bsum, SCAN_NB);
    scatter_scan_kernel<<<SCAN_NB, SCAN_B, 0, stream>>>(deg, bsum, row_ptr, invdeg, n, ne);
    fill_kernel<<<(ne + 255) / 256, 256, 0, stream>>>(src, dst, row_ptr, fill, col, ne);
    prep_weights<<<32, 256, 0, stream>>>(W1l, W1r, W2l, W2r, wf);
    cvt_bf16_kernel<<<(n * 32 + 255) / 256, 256, 0, stream>>>(x, xb, n * 32);

    agg_kernel<<<(n + 3) / 4, 256, 0, stream>>>(xb, row_ptr, col, invdeg, agg, n);
    gemm_mfma<<<(n + 63) / 64, 256, 0, stream>>>(agg, x, wf, wf + 32768, b1, h1, h1b, n, 1);
    agg_kernel<<<(n + 3) / 4, 256, 0, stream>>>(h1b, row_ptr, col, invdeg, agg, n);
    gemm_mfma<<<(n + 63) / 64, 256, 0, stream>>>(agg, h1, wf + 2 * 32768, wf + 3 * 32768, b2, h2,
                                                 (unsigned short*)0, n, 1);
    fc_kernel<<<(n + 3) / 4, 256, 0, stream>>>(h2, Wfc, bfc, out, n);
}

// Round 6
// 317.887 us; speedup vs baseline: 1.7173x; 1.0003x over previous
//
#include <hip/hip_runtime.h>

#define NN 50000
#define NE 800000
#define SCAN_B 256          // elements per scan block
#define SCAN_NB ((NN + SCAN_B - 1) / SCAN_B)   // 196
#define FILL_GRID 480       // 8 XCD-affine groups x 60 blocks

typedef short short8 __attribute__((ext_vector_type(8)));
typedef short short4v __attribute__((ext_vector_type(4)));
typedef float f32x4 __attribute__((ext_vector_type(4)));

__device__ inline unsigned short bf16_rne(float f) {
    unsigned u = __float_as_uint(f);
    unsigned r = (u + 0x7fffu + ((u >> 16) & 1u)) >> 16;
    return (unsigned short)r;
}
__device__ inline float bf16_to_f32(unsigned short h) {
    return __uint_as_float((unsigned)h << 16);
}

// ---------------- CSR build ----------------
__global__ void hist_kernel(const int* __restrict__ dst, int* __restrict__ deg, int ne) {
    int e = blockIdx.x * blockDim.x + threadIdx.x;
    if (e < ne) atomicAdd(&deg[dst[e]], 1);
}

__global__ __launch_bounds__(SCAN_B) void block_sum_kernel(const int* __restrict__ deg,
                                                           int* __restrict__ bsum, int n) {
    __shared__ int s[SCAN_B];
    int i = blockIdx.x * SCAN_B + threadIdx.x;
    int v = (i < n) ? deg[i] : 0;
    s[threadIdx.x] = v;
    __syncthreads();
    for (int d = SCAN_B >> 1; d > 0; d >>= 1) {
        if (threadIdx.x < d) s[threadIdx.x] += s[threadIdx.x + d];
        __syncthreads();
    }
    if (threadIdx.x == 0) bsum[blockIdx.x] = s[0];
}

__global__ __launch_bounds__(SCAN_B) void scan_bsums_kernel(int* __restrict__ bsum, int nb) {
    __shared__ int s[SCAN_B];
    int t = threadIdx.x;
    s[t] = (t < nb) ? bsum[t] : 0;
    __syncthreads();
    for (int d = 1; d < SCAN_B; d <<= 1) {
        int v = (t >= d) ? s[t - d] : 0;
        __syncthreads();
        s[t] += v;
        __syncthreads();
    }
    if (t < nb) bsum[t] = s[t];   // inclusive
}

// emits row_ptr, a cursor copy (for fill's atomics), and inv_deg
__global__ __launch_bounds__(SCAN_B) void scatter_scan_kernel(const int* __restrict__ deg,
                                                              const int* __restrict__ bsum,
                                                              int* __restrict__ row_ptr,
                                                              int* __restrict__ cursor,
                                                              float* __restrict__ inv_deg,
                                                              int n, int ne) {
    __shared__ int s[SCAN_B];
    int t = threadIdx.x;
    int i = blockIdx.x * SCAN_B + t;
    int v = (i < n) ? deg[i] : 0;
    s[t] = v;
    __syncthreads();
    for (int d = 1; d < SCAN_B; d <<= 1) {
        int u = (t >= d) ? s[t - d] : 0;
        __syncthreads();
        s[t] += u;
        __syncthreads();
    }
    int base = (blockIdx.x == 0) ? 0 : bsum[blockIdx.x - 1];
    if (i < n) {
        int rp = base + s[t] - v;   // exclusive
        row_ptr[i] = rp;
        cursor[i] = rp;
        inv_deg[i] = 1.0f / (float)(v > 0 ? v : 1);
    }
    if (blockIdx.x == 0 && t == 0) row_ptr[n] = ne;
}

// windowed, XCD-affine fill: group g (= blockIdx&7, XCD round-robin heuristic)
// commits only edges with dst in its 6250-node window -> col writes cluster in
// a ~400KB region owned by one XCD's L2 -> full-line writebacks, no 64B-per-4B
// amplification. Edge list re-read 8x, coalesced, L2/L3-served.
__global__ __launch_bounds__(256) void fill_win_kernel(const int* __restrict__ src,
                                                       const int* __restrict__ dst,
                                                       int* __restrict__ cursor,
                                                       int* __restrict__ col, int ne) {
    int g = blockIdx.x & 7;
    int lo = g * (NN / 8);
    int hi = lo + (NN / 8);
    int stride = (FILL_GRID >> 3) * 256;
    for (int e = (blockIdx.x >> 3) * 256 + threadIdx.x; e < ne; e += stride) {
        int d = dst[e];
        if (d >= lo && d < hi) {
            int pos = atomicAdd(&cursor[d], 1);
            col[pos] = src[e];
        }
    }
}

// ---------------- fp32 -> bf16 feature convert (for gather) ----------------
__global__ __launch_bounds__(256) void cvt_bf16_kernel(const float* __restrict__ in,
                                                       unsigned short* __restrict__ out, int n4) {
    int i = blockIdx.x * 256 + threadIdx.x;     // one float4 per thread
    if (i >= n4) return;
    float4 v = ((const float4*)in)[i];
    short4v r;
    r[0] = (short)bf16_rne(v.x);
    r[1] = (short)bf16_rne(v.y);
    r[2] = (short)bf16_rne(v.z);
    r[3] = (short)bf16_rne(v.w);
    ((short4v*)out)[i] = r;
}

// ---------------- weight prep: split fp32 -> (hi,lo) bf16, fragment-ordered ----
// Layout per matrix (32768 shorts): [nt(8)][kc(4)][pl(2)][lane(64)][j(8)]
// frag semantics (16x16x32): B[k][n], n = lane&15, k = kc*32 + (lane>>4)*8 + j
__global__ __launch_bounds__(256) void prep_weights(const float* __restrict__ W0,
                                                    const float* __restrict__ W1,
                                                    const float* __restrict__ W2,
                                                    const float* __restrict__ W3,
                                                    short* __restrict__ wf) {
    int t = blockIdx.x * 256 + threadIdx.x;   // 8192 threads total
    int mat = t >> 11;
    const float* W = (mat == 0) ? W0 : (mat == 1) ? W1 : (mat == 2) ? W2 : W3;
    short* out = wf + (size_t)mat * 32768;
    int r = t & 2047;
    int nt = r >> 8;
    int kc = (r >> 6) & 3;
    int lane = r & 63;
    int n = nt * 16 + (lane & 15);
    int kbase = kc * 32 + ((lane >> 4) << 3);
    short8 vh, vl;
#pragma unroll
    for (int j = 0; j < 8; ++j) {
        float w = W[(size_t)(kbase + j) * 128 + n];
        unsigned short h = bf16_rne(w);
        unsigned short l = bf16_rne(w - bf16_to_f32(h));
        vh[j] = (short)h;
        vl[j] = (short)l;
    }
    size_t o = ((((size_t)nt * 4 + kc) * 2) * 64 + lane) * 8;
    *(short8*)(out + o) = vh;
    *(short8*)(out + o + 512) = vl;   // pl=1 plane is +64*8 shorts
}

// ---------------- mean aggregation over bf16 features, fp32 accumulate ------
// one wave per node; slot = lane>>4 handles edge e = beg + i*4 + slot, sub =
// lane&15 handles features [sub*8, sub*8+8). 16B/lane loads, 4 rows per load
// instruction, x2 unroll (8 rows in flight). Butterfly shfl_xor(16,32)
// combines the 4 slots; lanes 0..15 write the 512B output row.
__global__ __launch_bounds__(256) void agg_kernel(const unsigned short* __restrict__ hb,
                                                  const int* __restrict__ row_ptr,
                                                  const int* __restrict__ col,
                                                  const float* __restrict__ inv_deg,
                                                  float* __restrict__ out, int n) {
    int node = blockIdx.x * 4 + (threadIdx.x >> 6);
    if (node >= n) return;
    int lane = threadIdx.x & 63;
    int slot = lane >> 4, sub = lane & 15;
    int beg = row_ptr[node], end = row_ptr[node + 1];
    const unsigned short* base = hb + (sub << 3);
    float acc[8];
#pragma unroll
    for (int j = 0; j < 8; ++j) acc[j] = 0.f;

    int e = beg + slot;
    for (; e + 4 < end; e += 8) {
        int j0 = col[e];
        int j1 = col[e + 4];
        uint4 v0 = *(const uint4*)(base + ((size_t)j0 << 7));
        uint4 v1 = *(const uint4*)(base + ((size_t)j1 << 7));
        unsigned w0[4] = {v0.x, v0.y, v0.z, v0.w};
        unsigned w1[4] = {v1.x, v1.y, v1.z, v1.w};
#pragma unroll
        for (int d = 0; d < 4; ++d) {
            acc[2 * d + 0] += __uint_as_float(w0[d] << 16);
            acc[2 * d + 1] += __uint_as_float(w0[d] & 0xffff0000u);
            acc[2 * d + 0] += __uint_as_float(w1[d] << 16);
            acc[2 * d + 1] += __uint_as_float(w1[d] & 0xffff0000u);
        }
    }
    if (e < end) {
        int j0 = col[e];
        uint4 v0 = *(const uint4*)(base + ((size_t)j0 << 7));
        unsigned w0[4] = {v0.x, v0.y, v0.z, v0.w};
#pragma unroll
        for (int d = 0; d < 4; ++d) {
            acc[2 * d + 0] += __uint_as_float(w0[d] << 16);
            acc[2 * d + 1] += __uint_as_float(w0[d] & 0xffff0000u);
        }
    }
    // combine the 4 slots (butterfly over lane bits 4,5)
#pragma unroll
    for (int j = 0; j < 8; ++j) {
        acc[j] += __shfl_xor(acc[j], 16, 64);
        acc[j] += __shfl_xor(acc[j], 32, 64);
    }
    if (slot == 0) {
        float s = inv_deg[node];
        float* op = out + ((size_t)node << 7) + (sub << 3);
        float4 r0, r1;
        r0.x = acc[0] * s; r0.y = acc[1] * s; r0.z = acc[2] * s; r0.w = acc[3] * s;
        r1.x = acc[4] * s; r1.y = acc[5] * s; r1.z = acc[6] * s; r1.w = acc[7] * s;
        *(float4*)op = r0;
        *(float4*)(op + 4) = r1;
    }
}

// ---------------- fused dual GEMM via split-bf16 MFMA ----------------
__global__ __launch_bounds__(256) void gemm_mfma(const float* __restrict__ A0,
                                                 const float* __restrict__ A1,
                                                 const short* __restrict__ Wf0,
                                                 const short* __restrict__ Wf1,
                                                 const float* __restrict__ bias,
                                                 float* __restrict__ out,
                                                 unsigned short* __restrict__ outb,
                                                 int n, int relu) {
    int lane = threadIdx.x & 63;
    int wave = threadIdx.x >> 6;
    int quad = lane >> 4, m16 = lane & 15;
    int row_base = blockIdx.x * 64 + wave * 16;
    int arow = row_base + m16;
    if (arow > n - 1) arow = n - 1;            // clamp (padding rows never stored)

    f32x4 acc[8];
#pragma unroll
    for (int nt = 0; nt < 8; ++nt) acc[nt] = (f32x4){0.f, 0.f, 0.f, 0.f};

#pragma unroll
    for (int pass = 0; pass < 2; ++pass) {
        const float* A = pass ? A1 : A0;
        const short* Wf = pass ? Wf1 : Wf0;
        const float* ap = A + ((size_t)arow << 7) + (quad << 3);
#pragma unroll
        for (int kc = 0; kc < 4; ++kc) {
            float4 av0 = *(const float4*)(ap + kc * 32);
            float4 av1 = *(const float4*)(ap + kc * 32 + 4);
            float af[8] = {av0.x, av0.y, av0.z, av0.w, av1.x, av1.y, av1.z, av1.w};
            short8 ah, al;
#pragma unroll
            for (int j = 0; j < 8; ++j) {
                unsigned short h = bf16_rne(af[j]);
                ah[j] = (short)h;
                al[j] = (short)bf16_rne(af[j] - bf16_to_f32(h));
            }
            const short* wp = Wf + ((size_t)kc * 2 * 64 + lane) * 8;
#pragma unroll
            for (int nt = 0; nt < 8; ++nt) {
                short8 bh = *(const short8*)(wp + (size_t)nt * 4096);
                short8 bl = *(const short8*)(wp + (size_t)nt * 4096 + 512);
                acc[nt] = __builtin_amdgcn_mfma_f32_16x16x32_bf16(ah, bh, acc[nt], 0, 0, 0);
                acc[nt] = __builtin_amdgcn_mfma_f32_16x16x32_bf16(al, bh, acc[nt], 0, 0, 0);
                acc[nt] = __builtin_amdgcn_mfma_f32_16x16x32_bf16(ah, bl, acc[nt], 0, 0, 0);
            }
        }
    }

    // epilogue: C/D layout col = lane&15, row = quad*4 + reg
    float bcol[8];
#pragma unroll
    for (int nt = 0; nt < 8; ++nt) bcol[nt] = bias[nt * 16 + m16];
#pragma unroll
    for (int r = 0; r < 4; ++r) {
        int row = row_base + quad * 4 + r;
        if (row >= n) continue;
        float* op = out + ((size_t)row << 7) + m16;
        unsigned short* opb = outb ? (outb + ((size_t)row << 7) + m16) : (unsigned short*)0;
#pragma unroll
        for (int nt = 0; nt < 8; ++nt) {
            float v = acc[nt][r] + bcol[nt];
            if (relu) v = fmaxf(v, 0.f);
            op[nt * 16] = v;
            if (opb) opb[nt * 16] = bf16_rne(v);
        }
    }
}

// ---------------- final FC (128 -> 2) ----------------
__global__ __launch_bounds__(256) void fc_kernel(const float* __restrict__ h,
                                                 const float* __restrict__ Wfc,
                                                 const float* __restrict__ bfc,
                                                 float* __restrict__ out, int n) {
    int node = blockIdx.x * 4 + (threadIdx.x >> 6);
    if (node >= n) return;
    int lane = threadIdx.x & 63;
    float2 hv = *(const float2*)(h + ((size_t)node << 7) + (lane << 1));
    float4 w = *(const float4*)(Wfc + (lane << 2));
    float p0 = hv.x * w.x + hv.y * w.z;
    float p1 = hv.x * w.y + hv.y * w.w;
#pragma unroll
    for (int off = 32; off > 0; off >>= 1) {
        p0 += __shfl_down(p0, off);
        p1 += __shfl_down(p1, off);
    }
    if (lane == 0) {
        out[node * 2 + 0] = p0 + bfc[0];
        out[node * 2 + 1] = p1 + bfc[1];
    }
}

extern "C" void kernel_launch(void* const* d_in, const int* in_sizes, int n_in,
                              void* d_out, int out_size, void* d_ws, size_t ws_size,
                              hipStream_t stream) {
    const float* x   = (const float*)d_in[0];
    const int* edge  = (const int*)d_in[1];
    const float* W1l = (const float*)d_in[2];
    const float* W1r = (const float*)d_in[3];
    const float* b1  = (const float*)d_in[4];
    const float* W2l = (const float*)d_in[5];
    const float* W2r = (const float*)d_in[6];
    const float* b2  = (const float*)d_in[7];
    const float* Wfc = (const float*)d_in[8];
    const float* bfc = (const float*)d_in[9];
    float* out = (float*)d_out;

    const int n = NN, ne = NE;
    const int* src = edge;        // edge_index[0]
    const int* dst = edge + ne;   // edge_index[1]

    char* ws = (char*)d_ws;
    size_t off = 0;
    auto alloc = [&](size_t bytes) -> char* {
        char* p = ws + off;
        off = (off + bytes + 511) & ~(size_t)511;
        return p;
    };
    int* deg      = (int*)alloc((size_t)n * 4);
    int* row_ptr  = (int*)alloc((size_t)(n + 1) * 4);
    int* cursor   = (int*)alloc((size_t)n * 4);
    float* invdeg = (float*)alloc((size_t)n * 4);
    int* bsum     = (int*)alloc((size_t)SCAN_NB * 4);
    short* wf     = (short*)alloc((size_t)4 * 32768 * 2);   // 4 matrices, frag-ordered hi/lo
    int* col      = (int*)alloc((size_t)ne * 4);
    float* agg    = (float*)alloc((size_t)n * 128 * 4);
    float* h1     = (float*)alloc((size_t)n * 128 * 4);
    float* h2     = (float*)alloc((size_t)n * 128 * 4);
    unsigned short* xb  = (unsigned short*)alloc((size_t)n * 128 * 2);  // bf16 x
    unsigned short* h1b = (unsigned short*)alloc((size_t)n * 128 * 2);  // bf16 h1
    (void)ws_size; (void)in_sizes; (void)n_in; (void)out_size;

    // zero deg only (cursor/row_ptr are fully written by scatter_scan)
    hipMemsetAsync(deg, 0, (size_t)n * 4, stream);

    hist_kernel<<<(ne + 255) / 256, 256, 0, stream>>>(dst, deg, ne);
    block_sum_kernel<<<SCAN_NB, SCAN_B, 0, stream>>>(deg, bsum, n);
    scan_bsums_kernel<<<1, SCAN_B, 0, stream>>>(bsum, SCAN_NB);
    scatter_scan_kernel<<<SCAN_NB, SCAN_B, 0, stream>>>(deg, bsum, row_ptr, cursor, invdeg, n, ne);
    fill_win_kernel<<<FILL_GRID, 256, 0, stream>>>(src, dst, cursor, col, ne);
    prep_weights<<<32, 256, 0, stream>>>(W1l, W1r, W2l, W2r, wf);
    cvt_bf16_kernel<<<(n * 32 + 255) / 256, 256, 0, stream>>>(x, xb, n * 32);

    agg_kernel<<<(n + 3) / 4, 256, 0, stream>>>(xb, row_ptr, col, invdeg, agg, n);
    gemm_mfma<<<(n + 63) / 64, 256, 0, stream>>>(agg, x, wf, wf + 32768, b1, h1, h1b, n, 1);
    agg_kernel<<<(n + 3) / 4, 256, 0, stream>>>(h1b, row_ptr, col, invdeg, agg, n);
    gemm_mfma<<<(n + 63) / 64, 256, 0, stream>>>(agg, h1, wf + 2 * 32768, wf + 3 * 32768, b2, h2,
                                                 (unsigned short*)0, n, 1);
    fc_kernel<<<(n + 3) / 4, 256, 0, stream>>>(h2, Wfc, bfc, out, n);
}